// Round 5
// baseline (187.247 us; speedup 1.0000x reference)
//
#include <hip/hip_runtime.h>

#define PI_F 3.14159265358979323846f
#define SC (1.0f/65536.0f)

__device__ __forceinline__ float2 cmul(float2 a, float2 b){
  return make_float2(fmaf(a.x, b.x, -(a.y*b.y)), fmaf(a.x, b.y, a.y*b.x));
}

// kept (unshifted) frequency indices: [0,44) U [211,256); compact c: w<44 -> c=w, w>=211 -> c=w-167
__device__ __forceinline__ bool keepf(int k){ return (k < 44) || (k >= 211); }

// LDS anti-conflict swizzle on float2 index within a 256-entry FFT line (involution).
__device__ __forceinline__ int swz(int i){ return i ^ (((i >> 4) & 3) << 2); }

// 256-point complex FFT, radix-4 Stockham, block-barrier synced, swizzled LDS.
// One wave (64 lanes, j=lane) per line; all waves of the block call in lockstep.
// Input: A filled at swz() positions; caller must __syncthreads() before calling.
// Output: in A, plain order if !OSWZ else swz order. Ends with __syncthreads().
template<int SIGN, bool OSWZ>
__device__ __forceinline__ void fft256(float2* __restrict__ A, float2* __restrict__ B, int j){
  float2* src = A;
  float2* dst = B;
#pragma unroll
  for(int s = 0; s < 4; ++s){
    const int Ns = 1 << (2*s);
    const int jm = j & (Ns - 1);
    float2 tw1, tw2, tw3;
    if(s > 0){
      float ang = (float)SIGN * (2.0f * PI_F) * (float)jm / (float)(Ns * 4);
      float sn, cs;
      __sincosf(ang, &sn, &cs);
      tw1 = make_float2(cs, sn);
      tw2 = cmul(tw1, tw1);
      tw3 = cmul(tw2, tw1);
    }
    float2 v0 = src[swz(j)];
    float2 v1 = src[swz(j + 64)];
    float2 v2 = src[swz(j + 128)];
    float2 v3 = src[swz(j + 192)];
    if(s > 0){ v1 = cmul(v1, tw1); v2 = cmul(v2, tw2); v3 = cmul(v3, tw3); }
    float2 t0 = make_float2(v0.x + v2.x, v0.y + v2.y);
    float2 t1 = make_float2(v0.x - v2.x, v0.y - v2.y);
    float2 t2 = make_float2(v1.x + v3.x, v1.y + v3.y);
    float2 t3 = make_float2(v1.x - v3.x, v1.y - v3.y);
    float2 y0 = make_float2(t0.x + t2.x, t0.y + t2.y);
    float2 y2 = make_float2(t0.x - t2.x, t0.y - t2.y);
    float2 y1, y3;
    if (SIGN < 0){
      y1 = make_float2(t1.x + t3.y, t1.y - t3.x);
      y3 = make_float2(t1.x - t3.y, t1.y + t3.x);
    } else {
      y1 = make_float2(t1.x - t3.y, t1.y + t3.x);
      y3 = make_float2(t1.x + t3.y, t1.y - t3.x);
    }
    const int idxD = ((j >> (2*s)) << (2*s + 2)) + jm;
    if((s < 3) || OSWZ){
      dst[swz(idxD)]        = y0;
      dst[swz(idxD + Ns)]   = y1;
      dst[swz(idxD + 2*Ns)] = y2;
      dst[swz(idxD + 3*Ns)] = y3;
    } else {
      dst[idxD]        = y0;
      dst[idxD + Ns]   = y1;
      dst[idxD + 2*Ns] = y2;
      dst[idxD + 3*Ns] = y3;
    }
    float2* tp = src; src = dst; dst = tp;
    __syncthreads();
  }
}

// K1: d = target - refer, row FFT, keep 89 w, write compact TRANSPOSED dkwT[b][c][h].
//     Block 2048: composite weights into wbuf (weights staged in LDS first).
__global__ __launch_bounds__(256) void k_rowfft(const float* __restrict__ tgt,
                                                const float* __restrict__ ref,
                                                float2* __restrict__ dkwT,
                                                const float* __restrict__ w1g,
                                                const float* __restrict__ b1g,
                                                const float* __restrict__ w2g,
                                                const float* __restrict__ b2g,
                                                float* __restrict__ wbuf){
  __shared__ float2 A[4][256];
  __shared__ float2 Bb[4][256];
  const int tid = threadIdx.x;
  if(blockIdx.x == 2048){
    // overlay weight staging onto A/Bb
    float* w1s = (float*)A;                 // 1152 floats (4.6KB of 8KB)
    float* w2s = (float*)Bb;                // 1152 floats
    float* b1s = ((float*)A) + 1152;        // 64
    float* b2s = ((float*)A) + 1216;        // 2
    for(int t = tid; t < 1152; t += 256){ w1s[t] = w1g[t]; w2s[t] = w2g[t]; }
    if(tid < 64) b1s[tid] = b1g[tid];
    if(tid < 2)  b2s[tid] = b2g[tid];
    __syncthreads();
    // wbuf[0..100) Weff[oc][ic][uy][ux]; [100..102) beff;
    // [102..426) G[(oc*2+ic)][d][k9]; [426..444) Cb[oc][d]
    for(int t = tid; t < 444; t += 256){
      if(t < 100){
        const int ux = t % 5, uy = (t/5) % 5, ic = (t/25) & 1, oc = t/50;
        float acc = 0.f;
        for(int mc = 0; mc < 64; ++mc)
          for(int dy = 0; dy < 3; ++dy){
            int ky = uy - dy; if((unsigned)ky >= 3u) continue;
            for(int dx = 0; dx < 3; ++dx){
              int kx = ux - dx; if((unsigned)kx >= 3u) continue;
              acc = fmaf(w2s[((oc*64+mc)*3+dy)*3+dx], w1s[((mc*2+ic)*3+ky)*3+kx], acc);
            }
          }
        wbuf[t] = acc;
      } else if(t < 102){
        const int oc = t - 100;
        float acc = b2s[oc];
        for(int mc = 0; mc < 64; ++mc){
          float s = 0.f;
          for(int d = 0; d < 9; ++d) s += w2s[(oc*64+mc)*9 + d];
          acc = fmaf(s, b1s[mc], acc);
        }
        wbuf[t] = acc;
      } else if(t < 426){
        const int g = t - 102;
        const int oc = g / 162, r1 = g - oc*162;
        const int ic = r1 / 81,  r2 = r1 - ic*81;
        const int d  = r2 / 9,   k9 = r2 - d*9;
        float acc = 0.f;
        for(int mc = 0; mc < 64; ++mc)
          acc = fmaf(w2s[(oc*64+mc)*9 + d], w1s[(mc*2+ic)*9 + k9], acc);
        wbuf[t] = acc;
      } else {
        const int i = t - 426, oc = i / 9, d = i - oc*9;
        float acc = 0.f;
        for(int mc = 0; mc < 64; ++mc)
          acc = fmaf(w2s[(oc*64+mc)*9 + d], b1s[mc], acc);
        wbuf[t] = acc;
      }
    }
    return;
  }
  const int wv = tid >> 6, ln = tid & 63;
  const int line = blockIdx.x*4 + wv;
  const int b = line >> 8, h = line & 255;
  const size_t base0 = ((size_t)(b*2 + 0)*256 + h)*256;
  const size_t base1 = ((size_t)(b*2 + 1)*256 + h)*256;
  float4 tr = *(const float4*)(tgt + base0 + ln*4);
  float4 ti = *(const float4*)(tgt + base1 + ln*4);
  float4 rr = *(const float4*)(ref + base0 + ln*4);
  float4 ri = *(const float4*)(ref + base1 + ln*4);
  A[wv][swz(ln*4 + 0)] = make_float2(tr.x - rr.x, ti.x - ri.x);
  A[wv][swz(ln*4 + 1)] = make_float2(tr.y - rr.y, ti.y - ri.y);
  A[wv][swz(ln*4 + 2)] = make_float2(tr.z - rr.z, ti.z - ri.z);
  A[wv][swz(ln*4 + 3)] = make_float2(tr.w - rr.w, ti.w - ri.w);
  __syncthreads();
  fft256<-1,false>(A[wv], Bb[wv], ln);
  // cooperative transposed compact write: 89 c * 4 h, 32B chunks
  const int b0 = (blockIdx.x*4) >> 8;
  const int h0 = (blockIdx.x*4) & 255;
  for(int idx = tid; idx < 356; idx += 256){
    const int c = idx >> 2, hh = idx & 3;
    const int w = (c < 44) ? c : (c + 167);
    dkwT[(size_t)(b0*89 + c)*256 + h0 + hh] = A[hh][w];
  }
}

// K2: per kept column: FFT along H, mask, IFFT. Read dkwT rows, write dkwC[b][h][c].
__global__ __launch_bounds__(256) void k_colfft(const float2* __restrict__ dkwT,
                                                float2* __restrict__ dkwC){
  __shared__ float2 A[4][256];
  __shared__ float2 Bb[4][256];
  const int wv = threadIdx.x >> 6, ln = threadIdx.x & 63;
  const int lineIdx = blockIdx.x*4 + wv;   // 2848 total = b*89 + c
  const float4* src = (const float4*)(dkwT + (size_t)lineIdx*256);
  float4 p0 = src[ln];
  float4 p1 = src[ln + 64];
  A[wv][swz(2*ln + 0)]   = make_float2(p0.x, p0.y);
  A[wv][swz(2*ln + 1)]   = make_float2(p0.z, p0.w);
  A[wv][swz(2*ln + 128)] = make_float2(p1.x, p1.y);
  A[wv][swz(2*ln + 129)] = make_float2(p1.z, p1.w);
  __syncthreads();
  fft256<-1,true>(A[wv], Bb[wv], ln);
#pragma unroll
  for(int k = 0; k < 4; ++k){
    int r = ln + 64*k;
    if(!keepf(r)) A[wv][swz(r)] = make_float2(0.f, 0.f);
  }
  __syncthreads();
  fft256<1,false>(A[wv], Bb[wv], ln);
  for(int idx = threadIdx.x; idx < 1024; idx += 256){
    const int cw = idx & 3, h = idx >> 2;
    const int li = blockIdx.x*4 + cw;
    const int bb = li / 89, cc = li - bb*89;
    dkwC[((size_t)bb*256 + h)*89 + cc] = A[cw][h];
  }
}

// K3: per 8-row strip: block-barrier row-IFFT of 12 rows into LDS (+refer),
//     composite 5x5 conv with float4 pair reads, self-contained border fixup.
__global__ __launch_bounds__(256, 4) void k_strip(const float2* __restrict__ dkwC,
                                                  const float* __restrict__ ref,
                                                  const float* __restrict__ wb,
                                                  float* __restrict__ out){
  __shared__ __align__(16) float2 strip[12][264];   // strip idx = image_x + 2
  __shared__ float2 Bsc[4][256];
  __shared__ float wefs[102];
  __shared__ float Gs[324];
  __shared__ float Cbs[18];
  const int tid = threadIdx.x, wv = tid >> 6, ln = tid & 63;
  const int b = blockIdx.y, y0 = blockIdx.x * 8;

  for(int i = tid; i < 444; i += 256){
    float v = wb[i];
    if(i < 102) wefs[i] = v;
    else if(i < 426) Gs[i - 102] = v;
    else Cbs[i - 426] = v;
  }

  // ---- row IFFT: 3 rows per wave, lockstep block-barrier FFT ----
  for(int i = 0; i < 3; ++i){
    const int sr = wv*3 + i;
    const int gy = y0 - 2 + sr;
    const bool gv = ((unsigned)gy < 256u);
    const float2* row = dkwC + ((size_t)b*256 + (gv ? gy : 0))*89;
    float2* Arow = &strip[sr][2];
    // prefetch refer into regs (vmcnt-tracked; hides under LDS fill + FFT)
    float4 rr4 = make_float4(0,0,0,0), ri4 = make_float4(0,0,0,0);
    size_t base0 = 0, base1 = 0;
    if(gv){
      base0 = ((size_t)(b*2 + 0)*256 + gy)*256;
      base1 = ((size_t)(b*2 + 1)*256 + gy)*256;
      rr4 = *(const float4*)(ref + base0 + ln*4);
      ri4 = *(const float4*)(ref + base1 + ln*4);
    }
#pragma unroll
    for(int k = 0; k < 4; ++k){
      const int w = ln*4 + k;
      const int c = (w < 44) ? w : ((w >= 211) ? (w - 167) : -1);
      float2 v = make_float2(0.f, 0.f);
      if(gv && c >= 0) v = row[c];
      Arow[swz(w)] = v;
    }
    if(ln < 2){
      strip[sr][ln] = make_float2(0.f, 0.f);
      strip[sr][258 + ln] = make_float2(0.f, 0.f);
    }
    __syncthreads();
    fft256<1,false>(Arow, Bsc[wv], ln);
    if(gv){
      float4* a4 = (float4*)&Arow[ln*4];
      float4 q0 = a4[0], q1 = a4[1];     // 4 float2 = (re,im)x4
      a4[0] = make_float4(fmaf(q0.x, SC, rr4.x), fmaf(q0.y, SC, ri4.x),
                          fmaf(q0.z, SC, rr4.y), fmaf(q0.w, SC, ri4.y));
      a4[1] = make_float4(fmaf(q1.x, SC, rr4.z), fmaf(q1.y, SC, ri4.z),
                          fmaf(q1.z, SC, rr4.w), fmaf(q1.w, SC, ri4.w));
    }
  }
  __syncthreads();

  // ---- conv phase: thread = (row, pair-lane); pixel pairs (ox, ox+1), ox even ----
  const int rr_ = tid >> 5;          // 0..7
  const int pp  = tid & 31;
  const int oy  = y0 + rr_;
  const bool yin = (oy != 0) && (oy != 255);
  const size_t ob0 = ((size_t)(b*2 + 0)*256 + oy)*256;
  const size_t ob1 = ((size_t)(b*2 + 1)*256 + oy)*256;
#pragma unroll
  for(int j = 0; j < 4; ++j){
    const int ox = 2*pp + 64*j;
    float p0a = wefs[100], p0b = wefs[101];
    float p1a = p0a,       p1b = p0b;
#pragma unroll
    for(int uy = 0; uy < 5; ++uy){
      const float4* rp = (const float4*)&strip[rr_ + uy][ox];
      float4 q0 = rp[0], q1 = rp[1], q2 = rp[2];
      float tx[6] = {q0.x, q0.z, q1.x, q1.z, q2.x, q2.z};
      float ty[6] = {q0.y, q0.w, q1.y, q1.w, q2.y, q2.w};
#pragma unroll
      for(int u = 0; u < 5; ++u){
        const float wA = wefs[uy*5 + u],      wB = wefs[25 + uy*5 + u];
        const float wC = wefs[50 + uy*5 + u], wD = wefs[75 + uy*5 + u];
        p0a = fmaf(tx[u],   wA, fmaf(ty[u],   wB, p0a));
        p0b = fmaf(tx[u],   wC, fmaf(ty[u],   wD, p0b));
        p1a = fmaf(tx[u+1], wA, fmaf(ty[u+1], wB, p1a));
        p1b = fmaf(tx[u+1], wC, fmaf(ty[u+1], wD, p1b));
      }
    }
    if(yin){
      if(ox != 0 && ox != 254){
        *(float2*)(out + ob0 + ox) = make_float2(p0a, p1a);
        *(float2*)(out + ob1 + ox) = make_float2(p0b, p1b);
      } else if(ox == 0){
        out[ob0 + 1] = p1a; out[ob1 + 1] = p1b;
      } else { // ox == 254
        out[ob0 + 254] = p0a; out[ob1 + 254] = p0b;
      }
    }
  }

  // ---- border fixup: full recompute + G/Cb correction, all from strip LDS ----
  const int nb = 16 + ((y0 == 0) ? 254 : 0) + ((y0 == 248) ? 254 : 0);
  for(int idx = tid; idx < nb; idx += 256){
    int py2, ox2;
    if(idx < 16){ py2 = idx >> 1; ox2 = (idx & 1) ? 255 : 0; }
    else {
      int e = idx - 16;
      if(y0 == 0 && e < 254){ py2 = 0; ox2 = 1 + e; }
      else { if(y0 == 0) e -= 254; py2 = 7; ox2 = 1 + e; }
    }
    const int oy2 = y0 + py2;
    float a0 = wefs[100], a1 = wefs[101];
#pragma unroll
    for(int uy = 0; uy < 5; ++uy)
#pragma unroll
      for(int ux = 0; ux < 5; ++ux){
        const float2 v = strip[py2 + uy][ox2 + ux];
        const int wi = uy*5 + ux;
        a0 = fmaf(v.x, wefs[wi],      fmaf(v.y, wefs[25 + wi], a0));
        a1 = fmaf(v.x, wefs[50 + wi], fmaf(v.y, wefs[75 + wi], a1));
      }
    for(int dy = 0; dy < 3; ++dy)
      for(int dx = 0; dx < 3; ++dx){
        const int gy2 = oy2 + dy - 1, gx2 = ox2 + dx - 1;
        if((unsigned)gy2 < 256u && (unsigned)gx2 < 256u) continue;
        const int d = dy*3 + dx;
        float c0 = Cbs[d], c1 = Cbs[9 + d];
        for(int ky = 0; ky < 3; ++ky){
          const int sy = gy2 + ky - 1;
          if((unsigned)sy >= 256u) continue;
          const int sr2 = sy - y0 + 2;
          for(int kx = 0; kx < 3; ++kx){
            const int sx = gx2 + kx - 1;
            if((unsigned)sx >= 256u) continue;
            const float2 v = strip[sr2][2 + sx];
            const int k9 = ky*3 + kx;
            c0 += Gs[0*81 + d*9 + k9]*v.x + Gs[1*81 + d*9 + k9]*v.y;
            c1 += Gs[2*81 + d*9 + k9]*v.x + Gs[3*81 + d*9 + k9]*v.y;
          }
        }
        a0 -= c0; a1 -= c1;
      }
    out[((size_t)(b*2 + 0)*256 + oy2)*256 + ox2] = a0;
    out[((size_t)(b*2 + 1)*256 + oy2)*256 + ox2] = a1;
  }
}

extern "C" void kernel_launch(void* const* d_in, const int* in_sizes, int n_in,
                              void* d_out, int out_size, void* d_ws, size_t ws_size,
                              hipStream_t stream) {
  const float* tgt = (const float*)d_in[0];
  const float* ref = (const float*)d_in[1];
  const float* w1  = (const float*)d_in[2];
  const float* b1  = (const float*)d_in[3];
  const float* w2  = (const float*)d_in[4];
  const float* b2  = (const float*)d_in[5];
  float* out = (float*)d_out;

  // ws: dkwT @0 (5.84MB), dkwC @8MB (5.84MB), wbuf @16MB (444 f32)
  float2* dkwT = (float2*)d_ws;
  float2* dkwC = (float2*)((char*)d_ws + (size_t)8*1024*1024);
  float*  wbuf = (float*)((char*)d_ws + (size_t)16*1024*1024);

  k_rowfft<<<2049, 256, 0, stream>>>(tgt, ref, dkwT, w1, b1, w2, b2, wbuf);
  k_colfft<<<712,  256, 0, stream>>>(dkwT, dkwC);
  dim3 gs(32, 32);
  k_strip <<<gs,   256, 0, stream>>>(dkwC, ref, wbuf, out);
}

// Round 6
// 118.468 us; speedup vs baseline: 1.5806x; 1.5806x over previous
//
#include <hip/hip_runtime.h>

#define PI_F 3.14159265358979323846f
#define SC (1.0f/65536.0f)

__device__ __forceinline__ float2 cmul(float2 a, float2 b){
  return make_float2(fmaf(a.x, b.x, -(a.y*b.y)), fmaf(a.x, b.y, a.y*b.x));
}

// kept (unshifted) frequency indices: [0,44) U [211,256); compact c: w<44 -> c=w, w>=211 -> c=w-167
__device__ __forceinline__ bool keepf(int k){ return (k < 44) || (k >= 211); }

// LDS anti-conflict swizzle on float2 index within a 256-entry FFT line (involution).
__device__ __forceinline__ int swz(int i){ return i ^ (((i >> 4) & 3) << 2); }

// 256-point complex FFT, radix-4 Stockham, block-barrier synced, swizzled LDS.
// One wave (64 lanes, j=lane) per line; all waves of the block call in lockstep.
// Input: A filled at swz() positions; caller must __syncthreads() before calling.
// Output: in A, plain order if !OSWZ else swz order. Ends with __syncthreads().
template<int SIGN, bool OSWZ>
__device__ __forceinline__ void fft256(float2* __restrict__ A, float2* __restrict__ B, int j){
  float2* src = A;
  float2* dst = B;
#pragma unroll
  for(int s = 0; s < 4; ++s){
    const int Ns = 1 << (2*s);
    const int jm = j & (Ns - 1);
    float2 tw1, tw2, tw3;
    if(s > 0){
      float ang = (float)SIGN * (2.0f * PI_F) * (float)jm / (float)(Ns * 4);
      float sn, cs;
      __sincosf(ang, &sn, &cs);
      tw1 = make_float2(cs, sn);
      tw2 = cmul(tw1, tw1);
      tw3 = cmul(tw2, tw1);
    }
    float2 v0 = src[swz(j)];
    float2 v1 = src[swz(j + 64)];
    float2 v2 = src[swz(j + 128)];
    float2 v3 = src[swz(j + 192)];
    if(s > 0){ v1 = cmul(v1, tw1); v2 = cmul(v2, tw2); v3 = cmul(v3, tw3); }
    float2 t0 = make_float2(v0.x + v2.x, v0.y + v2.y);
    float2 t1 = make_float2(v0.x - v2.x, v0.y - v2.y);
    float2 t2 = make_float2(v1.x + v3.x, v1.y + v3.y);
    float2 t3 = make_float2(v1.x - v3.x, v1.y - v3.y);
    float2 y0 = make_float2(t0.x + t2.x, t0.y + t2.y);
    float2 y2 = make_float2(t0.x - t2.x, t0.y - t2.y);
    float2 y1, y3;
    if (SIGN < 0){
      y1 = make_float2(t1.x + t3.y, t1.y - t3.x);
      y3 = make_float2(t1.x - t3.y, t1.y + t3.x);
    } else {
      y1 = make_float2(t1.x - t3.y, t1.y + t3.x);
      y3 = make_float2(t1.x + t3.y, t1.y - t3.x);
    }
    const int idxD = ((j >> (2*s)) << (2*s + 2)) + jm;
    if((s < 3) || OSWZ){
      dst[swz(idxD)]        = y0;
      dst[swz(idxD + Ns)]   = y1;
      dst[swz(idxD + 2*Ns)] = y2;
      dst[swz(idxD + 3*Ns)] = y3;
    } else {
      dst[idxD]        = y0;
      dst[idxD + Ns]   = y1;
      dst[idxD + 2*Ns] = y2;
      dst[idxD + 3*Ns] = y3;
    }
    float2* tp = src; src = dst; dst = tp;
    __syncthreads();
  }
}

// K1: d = target - refer, row FFT, keep 89 w, write compact TRANSPOSED dkwT[b][c][h].
//     Block 2048: composite weights into wbuf (weights staged in LDS first).
__global__ __launch_bounds__(256) void k_rowfft(const float* __restrict__ tgt,
                                                const float* __restrict__ ref,
                                                float2* __restrict__ dkwT,
                                                const float* __restrict__ w1g,
                                                const float* __restrict__ b1g,
                                                const float* __restrict__ w2g,
                                                const float* __restrict__ b2g,
                                                float* __restrict__ wbuf){
  __shared__ float2 A[4][256];
  __shared__ float2 Bb[4][256];
  const int tid = threadIdx.x;
  if(blockIdx.x == 2048){
    // overlay weight staging onto A/Bb
    float* w1s = (float*)A;                 // 1152 floats (4.6KB of 8KB)
    float* w2s = (float*)Bb;                // 1152 floats
    float* b1s = ((float*)A) + 1152;        // 64
    float* b2s = ((float*)A) + 1216;        // 2
    for(int t = tid; t < 1152; t += 256){ w1s[t] = w1g[t]; w2s[t] = w2g[t]; }
    if(tid < 64) b1s[tid] = b1g[tid];
    if(tid < 2)  b2s[tid] = b2g[tid];
    __syncthreads();
    // wbuf[0..100) Weff[oc][ic][uy][ux]; [100..102) beff;
    // [102..426) G[(oc*2+ic)][d][k9]; [426..444) Cb[oc][d]
    for(int t = tid; t < 444; t += 256){
      if(t < 100){
        const int ux = t % 5, uy = (t/5) % 5, ic = (t/25) & 1, oc = t/50;
        float acc = 0.f;
        for(int mc = 0; mc < 64; ++mc)
          for(int dy = 0; dy < 3; ++dy){
            int ky = uy - dy; if((unsigned)ky >= 3u) continue;
            for(int dx = 0; dx < 3; ++dx){
              int kx = ux - dx; if((unsigned)kx >= 3u) continue;
              acc = fmaf(w2s[((oc*64+mc)*3+dy)*3+dx], w1s[((mc*2+ic)*3+ky)*3+kx], acc);
            }
          }
        wbuf[t] = acc;
      } else if(t < 102){
        const int oc = t - 100;
        float acc = b2s[oc];
        for(int mc = 0; mc < 64; ++mc){
          float s = 0.f;
          for(int d = 0; d < 9; ++d) s += w2s[(oc*64+mc)*9 + d];
          acc = fmaf(s, b1s[mc], acc);
        }
        wbuf[t] = acc;
      } else if(t < 426){
        const int g = t - 102;
        const int oc = g / 162, r1 = g - oc*162;
        const int ic = r1 / 81,  r2 = r1 - ic*81;
        const int d  = r2 / 9,   k9 = r2 - d*9;
        float acc = 0.f;
        for(int mc = 0; mc < 64; ++mc)
          acc = fmaf(w2s[(oc*64+mc)*9 + d], w1s[(mc*2+ic)*9 + k9], acc);
        wbuf[t] = acc;
      } else {
        const int i = t - 426, oc = i / 9, d = i - oc*9;
        float acc = 0.f;
        for(int mc = 0; mc < 64; ++mc)
          acc = fmaf(w2s[(oc*64+mc)*9 + d], b1s[mc], acc);
        wbuf[t] = acc;
      }
    }
    return;
  }
  const int wv = tid >> 6, ln = tid & 63;
  const int line = blockIdx.x*4 + wv;
  const int b = line >> 8, h = line & 255;
  const size_t base0 = ((size_t)(b*2 + 0)*256 + h)*256;
  const size_t base1 = ((size_t)(b*2 + 1)*256 + h)*256;
  float4 tr = *(const float4*)(tgt + base0 + ln*4);
  float4 ti = *(const float4*)(tgt + base1 + ln*4);
  float4 rr = *(const float4*)(ref + base0 + ln*4);
  float4 ri = *(const float4*)(ref + base1 + ln*4);
  A[wv][swz(ln*4 + 0)] = make_float2(tr.x - rr.x, ti.x - ri.x);
  A[wv][swz(ln*4 + 1)] = make_float2(tr.y - rr.y, ti.y - ri.y);
  A[wv][swz(ln*4 + 2)] = make_float2(tr.z - rr.z, ti.z - ri.z);
  A[wv][swz(ln*4 + 3)] = make_float2(tr.w - rr.w, ti.w - ri.w);
  __syncthreads();
  fft256<-1,false>(A[wv], Bb[wv], ln);
  // cooperative transposed compact write: 89 c * 4 h, 32B chunks
  const int b0 = (blockIdx.x*4) >> 8;
  const int h0 = (blockIdx.x*4) & 255;
  for(int idx = tid; idx < 356; idx += 256){
    const int c = idx >> 2, hh = idx & 3;
    const int w = (c < 44) ? c : (c + 167);
    dkwT[(size_t)(b0*89 + c)*256 + h0 + hh] = A[hh][w];
  }
}

// K2: per kept column: FFT along H, mask, IFFT. Read dkwT rows, write dkwC[b][h][c].
__global__ __launch_bounds__(256) void k_colfft(const float2* __restrict__ dkwT,
                                                float2* __restrict__ dkwC){
  __shared__ float2 A[4][256];
  __shared__ float2 Bb[4][256];
  const int wv = threadIdx.x >> 6, ln = threadIdx.x & 63;
  const int lineIdx = blockIdx.x*4 + wv;   // 2848 total = b*89 + c
  const float4* src = (const float4*)(dkwT + (size_t)lineIdx*256);
  float4 p0 = src[ln];
  float4 p1 = src[ln + 64];
  A[wv][swz(2*ln + 0)]   = make_float2(p0.x, p0.y);
  A[wv][swz(2*ln + 1)]   = make_float2(p0.z, p0.w);
  A[wv][swz(2*ln + 128)] = make_float2(p1.x, p1.y);
  A[wv][swz(2*ln + 129)] = make_float2(p1.z, p1.w);
  __syncthreads();
  fft256<-1,true>(A[wv], Bb[wv], ln);
#pragma unroll
  for(int k = 0; k < 4; ++k){
    int r = ln + 64*k;
    if(!keepf(r)) A[wv][swz(r)] = make_float2(0.f, 0.f);
  }
  __syncthreads();
  fft256<1,false>(A[wv], Bb[wv], ln);
  for(int idx = threadIdx.x; idx < 1024; idx += 256){
    const int cw = idx & 3, h = idx >> 2;
    const int li = blockIdx.x*4 + cw;
    const int bb = li / 89, cc = li - bb*89;
    dkwC[((size_t)bb*256 + h)*89 + cc] = A[cw][h];
  }
}

// K3: per 8-row strip: block-barrier row-IFFT of 12 rows into LDS (+refer),
//     composite 5x5 conv with float4 pair reads, self-contained border fixup.
// NOTE: no min-waves launch bound — capping VGPRs to 64 caused ~400MB of
// scratch spill traffic (round 5: FETCH 147MB, WRITE 267MB, 150+ us).
__global__ __launch_bounds__(256) void k_strip(const float2* __restrict__ dkwC,
                                               const float* __restrict__ ref,
                                               const float* __restrict__ wb,
                                               float* __restrict__ out){
  __shared__ __align__(16) float2 strip[12][264];   // strip idx = image_x + 2
  __shared__ float2 Bsc[4][256];
  __shared__ float wefs[102];
  __shared__ float Gs[324];
  __shared__ float Cbs[18];
  const int tid = threadIdx.x, wv = tid >> 6, ln = tid & 63;
  const int b = blockIdx.y, y0 = blockIdx.x * 8;

  for(int i = tid; i < 444; i += 256){
    float v = wb[i];
    if(i < 102) wefs[i] = v;
    else if(i < 426) Gs[i - 102] = v;
    else Cbs[i - 426] = v;
  }

  // ---- row IFFT: 3 rows per wave, lockstep block-barrier FFT ----
  for(int i = 0; i < 3; ++i){
    const int sr = wv*3 + i;
    const int gy = y0 - 2 + sr;
    const bool gv = ((unsigned)gy < 256u);
    const float2* row = dkwC + ((size_t)b*256 + (gv ? gy : 0))*89;
    float2* Arow = &strip[sr][2];
    // prefetch refer into regs (vmcnt-tracked; hides under LDS fill + FFT)
    float4 rr4 = make_float4(0,0,0,0), ri4 = make_float4(0,0,0,0);
    if(gv){
      const size_t base0 = ((size_t)(b*2 + 0)*256 + gy)*256;
      const size_t base1 = ((size_t)(b*2 + 1)*256 + gy)*256;
      rr4 = *(const float4*)(ref + base0 + ln*4);
      ri4 = *(const float4*)(ref + base1 + ln*4);
    }
#pragma unroll
    for(int k = 0; k < 4; ++k){
      const int w = ln*4 + k;
      const int c = (w < 44) ? w : ((w >= 211) ? (w - 167) : -1);
      float2 v = make_float2(0.f, 0.f);
      if(gv && c >= 0) v = row[c];
      Arow[swz(w)] = v;
    }
    if(ln < 2){
      strip[sr][ln] = make_float2(0.f, 0.f);
      strip[sr][258 + ln] = make_float2(0.f, 0.f);
    }
    __syncthreads();
    fft256<1,false>(Arow, Bsc[wv], ln);
    if(gv){
      float4* a4 = (float4*)&Arow[ln*4];
      float4 q0 = a4[0], q1 = a4[1];     // 4 float2 = (re,im)x4
      a4[0] = make_float4(fmaf(q0.x, SC, rr4.x), fmaf(q0.y, SC, ri4.x),
                          fmaf(q0.z, SC, rr4.y), fmaf(q0.w, SC, ri4.y));
      a4[1] = make_float4(fmaf(q1.x, SC, rr4.z), fmaf(q1.y, SC, ri4.z),
                          fmaf(q1.z, SC, rr4.w), fmaf(q1.w, SC, ri4.w));
    }
  }
  __syncthreads();

  // ---- conv phase: thread = (row, pair-lane); pixel pairs (ox, ox+1), ox even ----
  const int rr_ = tid >> 5;          // 0..7
  const int pp  = tid & 31;
  const int oy  = y0 + rr_;
  const bool yin = (oy != 0) && (oy != 255);
  const size_t ob0 = ((size_t)(b*2 + 0)*256 + oy)*256;
  const size_t ob1 = ((size_t)(b*2 + 1)*256 + oy)*256;
#pragma unroll
  for(int j = 0; j < 4; ++j){
    const int ox = 2*pp + 64*j;
    float p0a = wefs[100], p0b = wefs[101];
    float p1a = p0a,       p1b = p0b;
#pragma unroll
    for(int uy = 0; uy < 5; ++uy){
      const float4* rp = (const float4*)&strip[rr_ + uy][ox];
      const float4 q0 = rp[0], q1 = rp[1], q2 = rp[2];
      const float* wA = &wefs[uy*5];
      const float* wB = &wefs[25 + uy*5];
      const float* wC = &wefs[50 + uy*5];
      const float* wD = &wefs[75 + uy*5];
      // u=0..4 over (q0.x,q0.z,q1.x,q1.z,q2.x) re / (q0.y,q0.w,q1.y,q1.w,q2.y) im
      p0a = fmaf(q0.x, wA[0], fmaf(q0.y, wB[0], p0a));
      p0b = fmaf(q0.x, wC[0], fmaf(q0.y, wD[0], p0b));
      p1a = fmaf(q0.z, wA[0], fmaf(q0.w, wB[0], p1a));
      p1b = fmaf(q0.z, wC[0], fmaf(q0.w, wD[0], p1b));
      p0a = fmaf(q0.z, wA[1], fmaf(q0.w, wB[1], p0a));
      p0b = fmaf(q0.z, wC[1], fmaf(q0.w, wD[1], p0b));
      p1a = fmaf(q1.x, wA[1], fmaf(q1.y, wB[1], p1a));
      p1b = fmaf(q1.x, wC[1], fmaf(q1.y, wD[1], p1b));
      p0a = fmaf(q1.x, wA[2], fmaf(q1.y, wB[2], p0a));
      p0b = fmaf(q1.x, wC[2], fmaf(q1.y, wD[2], p0b));
      p1a = fmaf(q1.z, wA[2], fmaf(q1.w, wB[2], p1a));
      p1b = fmaf(q1.z, wC[2], fmaf(q1.w, wD[2], p1b));
      p0a = fmaf(q1.z, wA[3], fmaf(q1.w, wB[3], p0a));
      p0b = fmaf(q1.z, wC[3], fmaf(q1.w, wD[3], p0b));
      p1a = fmaf(q2.x, wA[3], fmaf(q2.y, wB[3], p1a));
      p1b = fmaf(q2.x, wC[3], fmaf(q2.y, wD[3], p1b));
      p0a = fmaf(q2.x, wA[4], fmaf(q2.y, wB[4], p0a));
      p0b = fmaf(q2.x, wC[4], fmaf(q2.y, wD[4], p0b));
      p1a = fmaf(q2.z, wA[4], fmaf(q2.w, wB[4], p1a));
      p1b = fmaf(q2.z, wC[4], fmaf(q2.w, wD[4], p1b));
    }
    if(yin){
      if(ox != 0 && ox != 254){
        *(float2*)(out + ob0 + ox) = make_float2(p0a, p1a);
        *(float2*)(out + ob1 + ox) = make_float2(p0b, p1b);
      } else if(ox == 0){
        out[ob0 + 1] = p1a; out[ob1 + 1] = p1b;
      } else { // ox == 254
        out[ob0 + 254] = p0a; out[ob1 + 254] = p0b;
      }
    }
  }

  // ---- border fixup: full recompute + G/Cb correction, all from strip LDS ----
  const int nb = 16 + ((y0 == 0) ? 254 : 0) + ((y0 == 248) ? 254 : 0);
  for(int idx = tid; idx < nb; idx += 256){
    int py2, ox2;
    if(idx < 16){ py2 = idx >> 1; ox2 = (idx & 1) ? 255 : 0; }
    else {
      int e = idx - 16;
      if(y0 == 0 && e < 254){ py2 = 0; ox2 = 1 + e; }
      else { if(y0 == 0) e -= 254; py2 = 7; ox2 = 1 + e; }
    }
    const int oy2 = y0 + py2;
    float a0 = wefs[100], a1 = wefs[101];
#pragma unroll
    for(int uy = 0; uy < 5; ++uy)
#pragma unroll
      for(int ux = 0; ux < 5; ++ux){
        const float2 v = strip[py2 + uy][ox2 + ux];
        const int wi = uy*5 + ux;
        a0 = fmaf(v.x, wefs[wi],      fmaf(v.y, wefs[25 + wi], a0));
        a1 = fmaf(v.x, wefs[50 + wi], fmaf(v.y, wefs[75 + wi], a1));
      }
    for(int dy = 0; dy < 3; ++dy)
      for(int dx = 0; dx < 3; ++dx){
        const int gy2 = oy2 + dy - 1, gx2 = ox2 + dx - 1;
        if((unsigned)gy2 < 256u && (unsigned)gx2 < 256u) continue;
        const int d = dy*3 + dx;
        float c0 = Cbs[d], c1 = Cbs[9 + d];
        for(int ky = 0; ky < 3; ++ky){
          const int sy = gy2 + ky - 1;
          if((unsigned)sy >= 256u) continue;
          const int sr2 = sy - y0 + 2;
          for(int kx = 0; kx < 3; ++kx){
            const int sx = gx2 + kx - 1;
            if((unsigned)sx >= 256u) continue;
            const float2 v = strip[sr2][2 + sx];
            const int k9 = ky*3 + kx;
            c0 += Gs[0*81 + d*9 + k9]*v.x + Gs[1*81 + d*9 + k9]*v.y;
            c1 += Gs[2*81 + d*9 + k9]*v.x + Gs[3*81 + d*9 + k9]*v.y;
          }
        }
        a0 -= c0; a1 -= c1;
      }
    out[((size_t)(b*2 + 0)*256 + oy2)*256 + ox2] = a0;
    out[((size_t)(b*2 + 1)*256 + oy2)*256 + ox2] = a1;
  }
}

extern "C" void kernel_launch(void* const* d_in, const int* in_sizes, int n_in,
                              void* d_out, int out_size, void* d_ws, size_t ws_size,
                              hipStream_t stream) {
  const float* tgt = (const float*)d_in[0];
  const float* ref = (const float*)d_in[1];
  const float* w1  = (const float*)d_in[2];
  const float* b1  = (const float*)d_in[3];
  const float* w2  = (const float*)d_in[4];
  const float* b2  = (const float*)d_in[5];
  float* out = (float*)d_out;

  // ws: dkwT @0 (5.84MB), dkwC @8MB (5.84MB), wbuf @16MB (444 f32)
  float2* dkwT = (float2*)d_ws;
  float2* dkwC = (float2*)((char*)d_ws + (size_t)8*1024*1024);
  float*  wbuf = (float*)((char*)d_ws + (size_t)16*1024*1024);

  k_rowfft<<<2049, 256, 0, stream>>>(tgt, ref, dkwT, w1, b1, w2, b2, wbuf);
  k_colfft<<<712,  256, 0, stream>>>(dkwT, dkwC);
  dim3 gs(32, 32);
  k_strip <<<gs,   256, 0, stream>>>(dkwC, ref, wbuf, out);
}